// Round 1
// baseline (233.718 us; speedup 1.0000x reference)
//
#include <hip/hip_runtime.h>

// Problem shape (from reference): B=32, C=256, H=W=64
#define BATCH 32
#define CHANS 256
#define HWSZ  4096                 // 64*64
#define PER_CH_COUNT (BATCH * HWSZ)   // 131072
#define INV_COUNT (1.0f / 131072.0f)
#define HIST_N 10000

// One block per (b, c) slab of 4096 contiguous floats.
// Fused: copy slab to output + abs-sum reduce + one atomicAdd per block.
__global__ __launch_bounds__(256) void fused_copy_reduce(
    const float* __restrict__ in, float* __restrict__ out,
    float* __restrict__ chan_acc /* [CHANS] zeroed accumulators */) {
    const int slab = blockIdx.x;           // 0 .. BATCH*CHANS-1, = b*CHANS + c
    const int c = slab & (CHANS - 1);
    const size_t base = (size_t)slab * HWSZ;
    const float4* __restrict__ in4 = (const float4*)(in + base);
    float4* __restrict__ out4 = (float4*)(out + base);

    float s = 0.0f;
    // 4096 floats = 1024 float4; 256 threads x 4 iters, coalesced.
    #pragma unroll
    for (int i = 0; i < 4; ++i) {
        const int idx = threadIdx.x + i * 256;
        float4 v = in4[idx];
        out4[idx] = v;
        s += fabsf(v.x) + fabsf(v.y) + fabsf(v.z) + fabsf(v.w);
    }

    // wave64 shuffle reduction
    #pragma unroll
    for (int off = 32; off > 0; off >>= 1) s += __shfl_down(s, off, 64);

    __shared__ float wsum[4];
    const int lane = threadIdx.x & 63;
    const int wid = threadIdx.x >> 6;
    if (lane == 0) wsum[wid] = s;
    __syncthreads();
    if (threadIdx.x == 0) {
        atomicAdd(&chan_acc[c], wsum[0] + wsum[1] + wsum[2] + wsum[3]);
    }
}

// Finalize energy + hist (tiny).
__global__ __launch_bounds__(256) void finalize(
    const float* __restrict__ chan_acc,
    const float* __restrict__ td_energy,
    const float* __restrict__ td_hist,
    float* __restrict__ out_energy,
    float* __restrict__ out_hist) {
    const int i = blockIdx.x * blockDim.x + threadIdx.x;
    if (i < CHANS) out_energy[i] = td_energy[i] + chan_acc[i] * INV_COUNT;
    if (i < HIST_N) out_hist[i] = td_hist[i] + 1.0f;
}

extern "C" void kernel_launch(void* const* d_in, const int* in_sizes, int n_in,
                              void* d_out, int out_size, void* d_ws, size_t ws_size,
                              hipStream_t stream) {
    const float* data_in   = (const float*)d_in[0];
    const float* td_energy = (const float*)d_in[1];
    const float* td_hist   = (const float*)d_in[2];

    float* out_data   = (float*)d_out;
    float* out_energy = out_data + (size_t)BATCH * CHANS * HWSZ;
    float* out_hist   = out_energy + CHANS;

    float* chan_acc = (float*)d_ws;   // CHANS floats of scratch

    // ws is poisoned to 0xAA before every timed launch — zero our accumulators.
    hipMemsetAsync(chan_acc, 0, CHANS * sizeof(float), stream);

    fused_copy_reduce<<<BATCH * CHANS, 256, 0, stream>>>(data_in, out_data, chan_acc);

    finalize<<<(HIST_N + 255) / 256, 256, 0, stream>>>(
        chan_acc, td_energy, td_hist, out_energy, out_hist);
}